// Round 14
// baseline (46.630 us; speedup 1.0000x reference)
//
#include <hip/hip_runtime.h>

#define NN 1026   // nodes
#define NA 1024   // angles
#define BLK 1024
#define RSTR 132  // per-wave region stride (float2 slots): P[0..65], Q at +66
#define QOFF 66

// minimax atan2, max err ~2e-6 rad; inputs never both zero here
__device__ __forceinline__ float fast_atan2f(float y, float x) {
    float ax = __builtin_fabsf(x), ay = __builtin_fabsf(y);
    float mx = fmaxf(ax, ay), mn = fminf(ax, ay);
    float a  = mn * __builtin_amdgcn_rcpf(mx);
    float s  = a * a;
    float r  = fmaf(s, -0.0117212f,  0.05265332f);
    r = fmaf(s, r, -0.11643287f);
    r = fmaf(s, r,  0.19354346f);
    r = fmaf(s, r, -0.33262347f);
    r = fmaf(s, r,  0.99997726f);
    r *= a;
    if (ay > ax)  r = 1.57079637f - r;
    if (x < 0.0f) r = 3.14159274f - r;
    return copysignf(r, y);
}

__global__ __launch_bounds__(BLK)
void equil_kernel(const float* __restrict__ pos0,
                  const float* __restrict__ tip_pos,
                  const float* __restrict__ thetas_ss,
                  const int*   __restrict__ buckle,
                  const float* __restrict__ kstiff_p,
                  const float* __restrict__ ksoft_p,
                  const float* __restrict__ kstretch_p,
                  float* __restrict__ out)
{
    __shared__ float2 posA[NN], posB[NN];          // double-buffered positions
    __shared__ float2 PQ[2][17 * RSTR];            // 2 bufs x (16 wave regions + dump)

    const int b = blockIdx.x;
    const int t = threadIdx.x;
    const int w = t >> 6, l = t & 63;
    const int myslot = w * RSTR + l;
    const int hreg   = (w == 0) ? 16 : w - 1;      // left neighbor region (or dump)
    const int hslot  = hreg * RSTR + 64 + l;       // valid when l < 2
    const float k_str  = kstretch_p[0];
    const float k_sd   = kstiff_p[0] - ksoft_p[0];
    const float k4soft = 4.0f * ksoft_p[0];

    // ---- init: thread t computes angle t, owns node t+2 (free for t<=1022) ----
    const float2* p0g = (const float2*)(pos0 + (size_t)b * 2052);
    float2 myp;
    if (t < 1023) myp = p0g[t + 2];
    else          { myp.x = tip_pos[2*b]; myp.y = tip_pos[2*b+1]; }
    posA[t + 2] = myp;  posB[t + 2] = myp;
    if (t < 2) { posA[t] = p0g[t]; posB[t] = p0g[t]; }   // fixed nodes 0,1
    if (t < 2) {  // never-overwritten far-halo slots of wave 15 (read but discarded)
        PQ[t][15*RSTR + 65]        = make_float2(0.f, 0.f);
        PQ[t][15*RSTR + QOFF + 64] = make_float2(0.f, 0.f);
        PQ[t][15*RSTR + QOFF + 65] = make_float2(0.f, 0.f);
    }

    const float TH = thetas_ss[t];
    const int4 bk  = ((const int4*)buckle)[t];
    const float npl = (float)(bk.x + bk.y + bk.z + bk.w);   // #(pm==+1)
    float2 vel = make_float2(0.f, 0.f);
    __syncthreads();

#define AB_MATH(posR)                                                         \
        float2 pa = posR[t], pb = posR[t + 1];                                \
        float v1x = pb.x - pa.x,  v1y = pb.y - pa.y;                          \
        float v2x = myp.x - pb.x, v2y = myp.y - pb.y;                         \
        float l2a = fmaf(v1x, v1x, v1y * v1y);                                \
        float l2b = fmaf(v2x, v2x, v2y * v2y);                                \
        float cr  = v1x * v2y - v1y * v2x;                                    \
        float dt_ = fmaf(v1x, v2x, v1y * v2y);                                \
        float theta = fast_atan2f(cr, dt_);                                   \
        float cnt = (theta <  TH ? npl        : 0.f)                          \
                  + (theta > -TH ? 4.f - npl  : 0.f);                         \
        float K = fmaf(cnt, k_sd, k4soft);                                    \
        float m = K * (theta - TH);                                           \
        float ila = __builtin_amdgcn_rsqf(l2a);                               \
        float ilb = __builtin_amdgcn_rsqf(l2b);                               \
        float m1 = m * ila * ila;                                             \
        float m2 = m * ilb * ilb;                                             \
        float2 Bv; Bv.x = -m2 * v2y;  Bv.y =  m2 * v2x;                       \
        float sca = k_str * (1.0f - ila);                                     \
        float2 P;  P.x = fmaf(sca, v1x,  m1 * v1y);                           \
                   P.y = fmaf(sca, v1y, -m1 * v1x);                           \
        float2 Q;  Q.x = P.x - Bv.x;  Q.y = P.y - Bv.y;

    // ---- prime: step-0 stale halos (initial-state AB) into PQ[0] ----
    {
        AB_MATH(posA)
        if (l < 2) {
            float2* H = &PQ[0][hslot];
            H[0]    = P;
            H[QOFF] = Q;
        }
        (void)Bv;
    }
    __syncthreads();

#define STEP(posR, posW, CUR, NXT)                                            \
    {                                                                         \
        AB_MATH(posR)                                                         \
        float2* Wo = &PQ[CUR][myslot];                                        \
        Wo[0]    = P;                            /* ds_write2_b64 */          \
        Wo[QOFF] = Q;                                                         \
        if (l < 2) {                             /* stale halo for next step */\
            float2* H = &PQ[NXT][hslot];                                      \
            H[0]    = P;                                                      \
            H[QOFF] = Q;                                                      \
        }                                                                     \
        if (t == 1023) {                         /* fresh S_1024 (intra-wave) */\
            float scb = k_str * (1.0f - ilb);                                 \
            PQ[CUR][15*RSTR + 64] = make_float2(scb * v2x, scb * v2y);        \
        }                                                                     \
        __asm__ __volatile__("" ::: "memory");                                \
        const float2* R = &PQ[CUR][myslot];                                   \
        float2 Pn = R[2];                        /* ds_read2_b64 (2,67) */    \
        float2 Qm = R[QOFF + 1];                                              \
        if (t < 1023) {                                                       \
            float fx = Pn.x - Qm.x - Bv.x;                                    \
            float fy = Pn.y - Qm.y - Bv.y;                                    \
            vel.x += 0.001f * (fx - 2.0f * vel.x);                            \
            vel.y += 0.001f * (fy - 2.0f * vel.y);                            \
            myp.x += 0.001f * vel.x;                                          \
            myp.y += 0.001f * vel.y;                                          \
            posW[t + 2] = myp;                                                \
        }                                                                     \
        __syncthreads();                                                      \
    }

    for (int s2 = 0; s2 < 32; ++s2) {
        STEP(posA, posB, 0, 1)
        STEP(posB, posA, 1, 0)
    }
#undef STEP
#undef AB_MATH

    // ---- epilogue ----
    float2* o = (float2*)(out + (size_t)b * 2052);
    o[t + 2] = myp;              // t=1023 writes node 1025 = tip
    if (t < 2) o[t] = posA[t];
}

extern "C" void kernel_launch(void* const* d_in, const int* in_sizes, int n_in,
                              void* d_out, int out_size, void* d_ws, size_t ws_size,
                              hipStream_t stream) {
    const float* pos0   = (const float*)d_in[0];
    const float* tip    = (const float*)d_in[1];
    const float* thetas = (const float*)d_in[2];
    const int*   buckle = (const int*)  d_in[3];
    const float* ks     = (const float*)d_in[4];
    const float* ko     = (const float*)d_in[5];
    const float* kr     = (const float*)d_in[6];
    float* out = (float*)d_out;
    hipLaunchKernelGGL(equil_kernel, dim3(256), dim3(BLK), 0, stream,
                       pos0, tip, thetas, buckle, ks, ko, kr, out);
}